// Round 3
// baseline (876.505 us; speedup 1.0000x reference)
//
#include <hip/hip_runtime.h>

// Scatter-mean: 1M messages (f32, D=128) -> 50K nodes.
// Harness layout (forensically verified in prior session):
//   inputs:  d_in[0] = int32 node_ids[1M], d_in[1] = FLOAT32 messages[1M][128],
//            d_in[2] = int scalar num_nodes
//   output:  d_out = float32: [0,num_nodes) = ids as f32,
//            [num_nodes, num_nodes*(1+128)) = mean agg (row-major).
//
// v4 = v3 with the nontemporal builtins fixed: __builtin_nontemporal_load
// requires a native clang vector (ext_vector_type), not HIP's float2 class.
// Algorithm (counting sort, no f32 atomics):
//   A) u32 histogram of ids            (1M u32 atomics)
//   B) single-block exclusive scan     (50K bins)
//   C) scatter message indices by node (1M u32 fetch-adds, perm[1M])
//   D) one wave per node: pure-load segmented reduction, one store of mean.
// Rationale: atomic path was L2-atomic-bound (128M f32 atomics ~58 G/s ->
// 2232 us; memory roofline ~86 us). Workspace need:
// (num_messages + 3*num_nodes)*4 B = 4.6 MB; else fall back to atomic path.

typedef float f32x2 __attribute__((ext_vector_type(2)));

// ---------------- sort-based path ----------------

__global__ void hist_kernel(const int* __restrict__ ids,
                            unsigned* __restrict__ counts,
                            int num_messages) {
    int stride = gridDim.x * blockDim.x;
    for (int m = blockIdx.x * blockDim.x + threadIdx.x; m < num_messages; m += stride) {
        atomicAdd(&counts[ids[m]], 1u);
    }
}

// Single-block exclusive scan over num_nodes counts; writes offsets and a
// second copy (cursor) consumed destructively by the scatter phase.
__global__ void __launch_bounds__(1024)
scan_kernel(const unsigned* __restrict__ counts,
            unsigned* __restrict__ offsets,
            unsigned* __restrict__ cursor,
            int num_nodes) {
    __shared__ unsigned part[1024];
    int t = threadIdx.x;
    int chunk = (num_nodes + 1023) >> 10;
    int b = t * chunk;
    int e = min(b + chunk, num_nodes);
    unsigned s = 0;
    for (int i = b; i < e; ++i) s += counts[i];
    part[t] = s;
    __syncthreads();
    // Hillis-Steele inclusive scan over the 1024 partials.
    for (int off = 1; off < 1024; off <<= 1) {
        unsigned v = (t >= off) ? part[t - off] : 0u;
        __syncthreads();
        part[t] += v;
        __syncthreads();
    }
    unsigned run = (t == 0) ? 0u : part[t - 1];
    for (int i = b; i < e; ++i) {
        offsets[i] = run;
        cursor[i]  = run;
        run += counts[i];
    }
}

__global__ void scatter_idx_kernel(const int* __restrict__ ids,
                                   unsigned* __restrict__ cursor,
                                   unsigned* __restrict__ perm,
                                   int num_messages) {
    int m = blockIdx.x * 256 + threadIdx.x;
    if (m >= num_messages) return;
    unsigned pos = atomicAdd(&cursor[ids[m]], 1u);
    perm[pos] = m;
}

// One 64-lane wave per node. Lane l owns columns 2l, 2l+1 (f32x2): each
// message row read is 64 lanes x 8B = 512B contiguous (4 cachelines).
// 4-deep unroll with split accumulators keeps 4 perm loads + 4 row gathers
// in flight (dependent chain: perm ~200cy L2 -> row ~200-900cy HBM).
// Messages are read exactly once -> nontemporal keeps the 512MB stream
// out of L2, preserving L2 for perm/offsets/counts (12MB, reused).
__global__ void __launch_bounds__(256)
reduce_kernel(const float* __restrict__ msgs,
              const unsigned* __restrict__ offsets,
              const unsigned* __restrict__ counts,
              const unsigned* __restrict__ perm,
              float* __restrict__ out,
              int num_nodes) {
    int node = (blockIdx.x * 256 + threadIdx.x) >> 6;
    int lane = threadIdx.x & 63;
    if (node >= num_nodes) return;

    unsigned off = offsets[node];
    unsigned cnt = counts[node];
    int c2 = lane << 1;

    float ax0 = 0.f, ay0 = 0.f, ax1 = 0.f, ay1 = 0.f;
    float ax2 = 0.f, ay2 = 0.f, ax3 = 0.f, ay3 = 0.f;
    unsigned j = 0;
    for (; j + 4 <= cnt; j += 4) {
        unsigned m0 = perm[off + j + 0];
        unsigned m1 = perm[off + j + 1];
        unsigned m2 = perm[off + j + 2];
        unsigned m3 = perm[off + j + 3];
        const f32x2* p0 = reinterpret_cast<const f32x2*>(msgs + ((size_t)m0 << 7) + c2);
        const f32x2* p1 = reinterpret_cast<const f32x2*>(msgs + ((size_t)m1 << 7) + c2);
        const f32x2* p2 = reinterpret_cast<const f32x2*>(msgs + ((size_t)m2 << 7) + c2);
        const f32x2* p3 = reinterpret_cast<const f32x2*>(msgs + ((size_t)m3 << 7) + c2);
        f32x2 v0 = __builtin_nontemporal_load(p0);
        f32x2 v1 = __builtin_nontemporal_load(p1);
        f32x2 v2 = __builtin_nontemporal_load(p2);
        f32x2 v3 = __builtin_nontemporal_load(p3);
        ax0 += v0.x; ay0 += v0.y;
        ax1 += v1.x; ay1 += v1.y;
        ax2 += v2.x; ay2 += v2.y;
        ax3 += v3.x; ay3 += v3.y;
    }
    for (; j < cnt; ++j) {
        unsigned m0 = perm[off + j];
        const f32x2* p0 = reinterpret_cast<const f32x2*>(msgs + ((size_t)m0 << 7) + c2);
        f32x2 v0 = __builtin_nontemporal_load(p0);
        ax0 += v0.x; ay0 += v0.y;
    }

    float inv = 1.0f / fmaxf((float)cnt, 1.0f);   // cnt==0 -> writes zeros (matches ref)
    f32x2 r;
    r.x = ((ax0 + ax1) + (ax2 + ax3)) * inv;
    r.y = ((ay0 + ay1) + (ay2 + ay3)) * inv;
    __builtin_nontemporal_store(r, reinterpret_cast<f32x2*>(out + num_nodes + ((size_t)node << 7) + c2));

    if (lane == 0) out[node] = (float)node;       // ids region: exact f32 arange
}

// ---------------- fallback: previously-verified atomic path ----------------

__global__ void __launch_bounds__(256)
scatter_add_kernel(const int* __restrict__ ids,
                   const float* __restrict__ msgs,
                   float* __restrict__ sums,
                   float* __restrict__ fcounts,
                   int num_messages) {
    int tid = blockIdx.x * 256 + threadIdx.x;
    int msg = tid >> 5;
    if (msg >= num_messages) return;
    int g   = tid & 31;
    int col = g << 2;
    int id  = ids[msg];

    float4 v = *reinterpret_cast<const float4*>(msgs + ((size_t)msg << 7) + col);
    float* base = sums + ((size_t)id << 7) + col;
    unsafeAtomicAdd(base + 0, v.x);
    unsafeAtomicAdd(base + 1, v.y);
    unsafeAtomicAdd(base + 2, v.z);
    unsafeAtomicAdd(base + 3, v.w);
    if (g == 0) unsafeAtomicAdd(fcounts + id, 1.0f);
}

__global__ void __launch_bounds__(256)
finalize_kernel(float* __restrict__ out,
                const float* __restrict__ fcounts,
                int num_nodes) {
    int tid = blockIdx.x * 256 + threadIdx.x;
    if (tid < num_nodes) out[tid] = (float)tid;
    int t2 = tid - num_nodes;
    if (t2 >= 0 && t2 < num_nodes * 32) {
        int node = t2 >> 5;
        int col  = (t2 & 31) << 2;
        float inv = 1.0f / fmaxf(fcounts[node], 1.0f);
        float* p = out + num_nodes + ((size_t)node << 7) + col;
        float4 s = *reinterpret_cast<const float4*>(p);
        s.x *= inv; s.y *= inv; s.z *= inv; s.w *= inv;
        *reinterpret_cast<float4*>(p) = s;
    }
}

// ---------------- launch ----------------

extern "C" void kernel_launch(void* const* d_in, const int* in_sizes, int n_in,
                              void* d_out, int out_size, void* d_ws, size_t ws_size,
                              hipStream_t stream) {
    const int*   ids  = (const int*)d_in[0];
    const float* msgs = (const float*)d_in[1];
    int num_messages = in_sizes[0];
    int D            = in_sizes[1] / in_sizes[0];   // 128
    int num_nodes    = out_size / (D + 1);          // 50000

    float* out = (float*)d_out;

    size_t needed = ((size_t)num_messages + 3 * (size_t)num_nodes) * sizeof(unsigned);

    if (D == 128 && ws_size >= needed) {
        // sort-based path (no f32 atomics)
        unsigned* perm    = (unsigned*)d_ws;
        unsigned* counts  = perm + num_messages;
        unsigned* offsets = counts + num_nodes;
        unsigned* cursor  = offsets + num_nodes;

        (void)hipMemsetAsync(counts, 0, (size_t)num_nodes * sizeof(unsigned), stream);

        hist_kernel<<<2048, 256, 0, stream>>>(ids, counts, num_messages);
        scan_kernel<<<1, 1024, 0, stream>>>(counts, offsets, cursor, num_nodes);
        int blocksC = (num_messages + 255) / 256;
        scatter_idx_kernel<<<blocksC, 256, 0, stream>>>(ids, cursor, perm, num_messages);
        long long threadsD = (long long)num_nodes * 64;
        int blocksD = (int)((threadsD + 255) / 256);
        reduce_kernel<<<blocksD, 256, 0, stream>>>(msgs, offsets, counts, perm, out, num_nodes);
    } else {
        // fallback: verified atomic path
        float* sums    = out + num_nodes;
        float* fcounts = (float*)d_ws;

        (void)hipMemsetAsync(d_out, 0, (size_t)out_size * sizeof(float), stream);
        (void)hipMemsetAsync(d_ws, 0, (size_t)num_nodes * sizeof(float), stream);

        int threads1 = num_messages * (D / 4);
        int blocks1  = (threads1 + 255) / 256;
        scatter_add_kernel<<<blocks1, 256, 0, stream>>>(ids, msgs, sums, fcounts, num_messages);

        int threads2 = num_nodes + num_nodes * (D / 4);
        int blocks2  = (threads2 + 255) / 256;
        finalize_kernel<<<blocks2, 256, 0, stream>>>(out, fcounts, num_nodes);
    }
}

// Round 4
// 864.945 us; speedup vs baseline: 1.0134x; 1.0134x over previous
//
#include <hip/hip_runtime.h>

// Scatter-mean: 1M messages (f32, D=128) -> 50K nodes.
// Harness layout (forensically verified):
//   inputs:  d_in[0] = int32 node_ids[1M], d_in[1] = FLOAT32 messages[1M][128],
//            d_in[2] = int scalar num_nodes
//   output:  d_out = float32: [0,num_nodes) = ids as f32,
//            [num_nodes, num_nodes*(1+128)) = mean agg (row-major).
//
// v5 = v4 (counting sort, PASSED 876.5 us) with a wider reduce phase:
//   - reduce: float4 x 32-lane (2 rows per load instr, 8 rows in flight/iter,
//     16 B/lane sweet spot), cross-half combine via shfl_xor(32).
//   - hist: int4 id loads.
// Profile showed top-5 all harness 2GB poison fills (~315 us each); our
// kernels are each <315 us. This round disambiguates whether those fills sit
// inside the timed window (expect ~800 us) or our gather was slow (expect
// ~550-680 us).
// Phases: A) u32 histogram  B) single-block scan  C) index scatter (perm)
//         D) one wave per node: pure-load segmented reduction.
// Workspace: (num_messages + 3*num_nodes)*4 B = 4.6 MB; else atomic fallback.

typedef float f32x2 __attribute__((ext_vector_type(2)));
typedef float f32x4 __attribute__((ext_vector_type(4)));

// ---------------- sort-based path ----------------

__global__ void hist_kernel(const int* __restrict__ ids,
                            unsigned* __restrict__ counts,
                            int num_messages) {
    int n4 = num_messages >> 2;
    int stride = gridDim.x * blockDim.x;
    const int4* ids4 = reinterpret_cast<const int4*>(ids);
    for (int i = blockIdx.x * blockDim.x + threadIdx.x; i < n4; i += stride) {
        int4 v = ids4[i];
        atomicAdd(&counts[v.x], 1u);
        atomicAdd(&counts[v.y], 1u);
        atomicAdd(&counts[v.z], 1u);
        atomicAdd(&counts[v.w], 1u);
    }
    if (blockIdx.x == 0 && threadIdx.x == 0) {
        for (int m = n4 << 2; m < num_messages; ++m) atomicAdd(&counts[ids[m]], 1u);
    }
}

// Single-block exclusive scan over num_nodes counts; writes offsets and a
// second copy (cursor) consumed destructively by the scatter phase.
__global__ void __launch_bounds__(1024)
scan_kernel(const unsigned* __restrict__ counts,
            unsigned* __restrict__ offsets,
            unsigned* __restrict__ cursor,
            int num_nodes) {
    __shared__ unsigned part[1024];
    int t = threadIdx.x;
    int chunk = (num_nodes + 1023) >> 10;
    int b = t * chunk;
    int e = min(b + chunk, num_nodes);
    unsigned s = 0;
    for (int i = b; i < e; ++i) s += counts[i];
    part[t] = s;
    __syncthreads();
    for (int off = 1; off < 1024; off <<= 1) {
        unsigned v = (t >= off) ? part[t - off] : 0u;
        __syncthreads();
        part[t] += v;
        __syncthreads();
    }
    unsigned run = (t == 0) ? 0u : part[t - 1];
    for (int i = b; i < e; ++i) {
        offsets[i] = run;
        cursor[i]  = run;
        run += counts[i];
    }
}

__global__ void scatter_idx_kernel(const int* __restrict__ ids,
                                   unsigned* __restrict__ cursor,
                                   unsigned* __restrict__ perm,
                                   int num_messages) {
    int m = blockIdx.x * 256 + threadIdx.x;
    if (m >= num_messages) return;
    unsigned pos = atomicAdd(&cursor[ids[m]], 1u);
    perm[pos] = m;
}

// One 64-lane wave per node. Half-wave h (lane>>5) reads row j+h; lane&31
// owns 4 columns (float4, 16 B/lane): one load instruction covers TWO rows
// (2 x 512 B). 8 rows in flight per main-loop iteration via 4 accumulators.
// Messages are read exactly once -> nontemporal keeps the 512 MB stream from
// thrashing L2; perm/offsets/counts (12 MB, recently written) stay cached.
__global__ void __launch_bounds__(256)
reduce_kernel(const float* __restrict__ msgs,
              const unsigned* __restrict__ offsets,
              const unsigned* __restrict__ counts,
              const unsigned* __restrict__ perm,
              float* __restrict__ out,
              int num_nodes) {
    int node = (blockIdx.x * 256 + threadIdx.x) >> 6;
    int lane = threadIdx.x & 63;
    if (node >= num_nodes) return;

    unsigned off = offsets[node];
    unsigned cnt = counts[node];
    int half = lane >> 5;            // 0 or 1: which row of the pair
    int c4   = (lane & 31) << 2;     // column base

    f32x4 a0 = {0.f,0.f,0.f,0.f}, a1 = a0, a2 = a0, a3 = a0;
    unsigned j = 0;
    for (; j + 8 <= cnt; j += 8) {   // 8 rows, 4 load instrs, 4 KB in flight
        unsigned m0 = perm[off + j + 0 + half];
        unsigned m1 = perm[off + j + 2 + half];
        unsigned m2 = perm[off + j + 4 + half];
        unsigned m3 = perm[off + j + 6 + half];
        f32x4 v0 = __builtin_nontemporal_load(
            reinterpret_cast<const f32x4*>(msgs + ((size_t)m0 << 7) + c4));
        f32x4 v1 = __builtin_nontemporal_load(
            reinterpret_cast<const f32x4*>(msgs + ((size_t)m1 << 7) + c4));
        f32x4 v2 = __builtin_nontemporal_load(
            reinterpret_cast<const f32x4*>(msgs + ((size_t)m2 << 7) + c4));
        f32x4 v3 = __builtin_nontemporal_load(
            reinterpret_cast<const f32x4*>(msgs + ((size_t)m3 << 7) + c4));
        a0 += v0; a1 += v1; a2 += v2; a3 += v3;
    }
    for (; j + 2 <= cnt; j += 2) {   // row pairs
        unsigned m0 = perm[off + j + half];
        a0 += __builtin_nontemporal_load(
            reinterpret_cast<const f32x4*>(msgs + ((size_t)m0 << 7) + c4));
    }
    if (j + half < cnt) {            // last odd row (half 0 only reads row j)
        unsigned m0 = perm[off + j + half];
        a1 += __builtin_nontemporal_load(
            reinterpret_cast<const f32x4*>(msgs + ((size_t)m0 << 7) + c4));
    }

    f32x4 a = (a0 + a1) + (a2 + a3);
    // combine the two half-waves: lane l (<32) accumulates lane l+32
    a.x += __shfl_xor(a.x, 32);
    a.y += __shfl_xor(a.y, 32);
    a.z += __shfl_xor(a.z, 32);
    a.w += __shfl_xor(a.w, 32);

    if (half == 0) {
        float inv = 1.0f / fmaxf((float)cnt, 1.0f);  // cnt==0 -> zeros (matches ref)
        a.x *= inv; a.y *= inv; a.z *= inv; a.w *= inv;
        __builtin_nontemporal_store(a,
            reinterpret_cast<f32x4*>(out + num_nodes + ((size_t)node << 7) + c4));
        if (lane == 0) out[node] = (float)node;      // ids region: exact f32 arange
    }
}

// ---------------- fallback: previously-verified atomic path ----------------

__global__ void __launch_bounds__(256)
scatter_add_kernel(const int* __restrict__ ids,
                   const float* __restrict__ msgs,
                   float* __restrict__ sums,
                   float* __restrict__ fcounts,
                   int num_messages) {
    int tid = blockIdx.x * 256 + threadIdx.x;
    int msg = tid >> 5;
    if (msg >= num_messages) return;
    int g   = tid & 31;
    int col = g << 2;
    int id  = ids[msg];

    float4 v = *reinterpret_cast<const float4*>(msgs + ((size_t)msg << 7) + col);
    float* base = sums + ((size_t)id << 7) + col;
    unsafeAtomicAdd(base + 0, v.x);
    unsafeAtomicAdd(base + 1, v.y);
    unsafeAtomicAdd(base + 2, v.z);
    unsafeAtomicAdd(base + 3, v.w);
    if (g == 0) unsafeAtomicAdd(fcounts + id, 1.0f);
}

__global__ void __launch_bounds__(256)
finalize_kernel(float* __restrict__ out,
                const float* __restrict__ fcounts,
                int num_nodes) {
    int tid = blockIdx.x * 256 + threadIdx.x;
    if (tid < num_nodes) out[tid] = (float)tid;
    int t2 = tid - num_nodes;
    if (t2 >= 0 && t2 < num_nodes * 32) {
        int node = t2 >> 5;
        int col  = (t2 & 31) << 2;
        float inv = 1.0f / fmaxf(fcounts[node], 1.0f);
        float* p = out + num_nodes + ((size_t)node << 7) + col;
        float4 s = *reinterpret_cast<const float4*>(p);
        s.x *= inv; s.y *= inv; s.z *= inv; s.w *= inv;
        *reinterpret_cast<float4*>(p) = s;
    }
}

// ---------------- launch ----------------

extern "C" void kernel_launch(void* const* d_in, const int* in_sizes, int n_in,
                              void* d_out, int out_size, void* d_ws, size_t ws_size,
                              hipStream_t stream) {
    const int*   ids  = (const int*)d_in[0];
    const float* msgs = (const float*)d_in[1];
    int num_messages = in_sizes[0];
    int D            = in_sizes[1] / in_sizes[0];   // 128
    int num_nodes    = out_size / (D + 1);          // 50000

    float* out = (float*)d_out;

    size_t needed = ((size_t)num_messages + 3 * (size_t)num_nodes) * sizeof(unsigned);

    if (D == 128 && ws_size >= needed) {
        // sort-based path (no f32 atomics)
        unsigned* perm    = (unsigned*)d_ws;
        unsigned* counts  = perm + num_messages;
        unsigned* offsets = counts + num_nodes;
        unsigned* cursor  = offsets + num_nodes;

        (void)hipMemsetAsync(counts, 0, (size_t)num_nodes * sizeof(unsigned), stream);

        int n4 = num_messages >> 2;
        int blocksA = min(2048, (n4 + 255) / 256);
        hist_kernel<<<blocksA, 256, 0, stream>>>(ids, counts, num_messages);
        scan_kernel<<<1, 1024, 0, stream>>>(counts, offsets, cursor, num_nodes);
        int blocksC = (num_messages + 255) / 256;
        scatter_idx_kernel<<<blocksC, 256, 0, stream>>>(ids, cursor, perm, num_messages);
        long long threadsD = (long long)num_nodes * 64;
        int blocksD = (int)((threadsD + 255) / 256);
        reduce_kernel<<<blocksD, 256, 0, stream>>>(msgs, offsets, counts, perm, out, num_nodes);
    } else {
        // fallback: verified atomic path
        float* sums    = out + num_nodes;
        float* fcounts = (float*)d_ws;

        (void)hipMemsetAsync(d_out, 0, (size_t)out_size * sizeof(float), stream);
        (void)hipMemsetAsync(d_ws, 0, (size_t)num_nodes * sizeof(float), stream);

        int threads1 = num_messages * (D / 4);
        int blocks1  = (threads1 + 255) / 256;
        scatter_add_kernel<<<blocks1, 256, 0, stream>>>(ids, msgs, sums, fcounts, num_messages);

        int threads2 = num_nodes + num_nodes * (D / 4);
        int blocks2  = (threads2 + 255) / 256;
        finalize_kernel<<<blocks2, 256, 0, stream>>>(out, fcounts, num_nodes);
    }
}